// Round 11
// baseline (196.675 us; speedup 1.0000x reference)
//
#include <hip/hip_runtime.h>

// LaterallyConnectedLayer: B=16, NUM_FM=32, N_REPL=4, C=128, H=W=56, K_SZ=5
// Algebra:
//  - softmax map sums to 1 -> first conv never affects winners -> skipped
//  - winner sparsity: K_change and final conv only touch 32 of 128 channels
//  - padding = index remaps; activations in zero-ring-padded [60][64] frames
// R10: k3 latency-bound (MfmaUtil 9%, VALU 20%, 16 loads/kstep). Register
//      sliding window: window(dj,ks+2)==window(dj+1,ks), so keep 2 parity
//      sets of 5 windows (6 dwords each), rotate after odd ksteps, load only
//      1 new window/parity (3 loads) + 1-ahead A prefetch -> 4 loads/kstep.
//      Frag-build algebra byte-identical to the R9-verified code.

typedef __attribute__((ext_vector_type(8))) short short8;
typedef __attribute__((ext_vector_type(4))) float floatx4;

#define EPSF 1e-10f

__device__ __forceinline__ int map60(int r) {
  return r < 4 ? 5 - r : (r < 56 ? r - 2 : 109 - r);
}
__device__ __forceinline__ unsigned short f2bf(float x) {
  unsigned int u = __float_as_uint(x);
  u += 0x7fff + ((u >> 16) & 1);
  return (unsigned short)(u >> 16);
}
__device__ __forceinline__ float bf2f(unsigned int h) {
  return __uint_as_float((h & 0xffffu) << 16);
}
__device__ __forceinline__ short8 u4_to_s8(uint4 v) {
  union { uint4 u; short8 s; } cv;
  cv.u = v;
  return cv.s;
}

// k1: Abf[256 + bc*3840 + p] = bf16 zero-ring relu(A_sym + 0.1*noise);
//     s[bc] = fp32 interior sum. Quad-vectorized with scalar edge fallback.
__global__ __launch_bounds__(256) void k1_build(const float* __restrict__ A,
                                                const float* __restrict__ noise,
                                                unsigned short* __restrict__ Abf,
                                                float* __restrict__ s) {
  int bc = blockIdx.x;
  int b = bc >> 7, c = bc & 127;
  int fm = c & 31;
  const float* Abase = A + (size_t)(b * 32 + fm) * 3136;
  const float* nz = noise + (size_t)bc * 3136;
  unsigned short* outb = Abf + 256 + (size_t)bc * 3840;
  float local = 0.f;
  for (int q = threadIdx.x; q < 960; q += 256) {
    int r = q >> 4, qc = q & 15, col0 = qc << 2;
    int h = r - 2;
    float v0, v1, v2, v3;
    if (r < 2 || r > 57 || qc == 15) {
      v0 = v1 = v2 = v3 = 0.f;
    } else if (r >= 4 && r <= 55 && qc >= 1 && qc <= 13) {
      int w0 = col0 - 2;
      const float* ap = Abase + h * 56 + w0;
      const float* np = nz + h * 56 + w0;
      float2 a0 = *reinterpret_cast<const float2*>(ap);
      float2 a1 = *reinterpret_cast<const float2*>(ap + 2);
      float2 n0 = *reinterpret_cast<const float2*>(np);
      float2 n1 = *reinterpret_cast<const float2*>(np + 2);
      v0 = fmaxf(a0.x + 0.1f * n0.x, 0.f);
      v1 = fmaxf(a0.y + 0.1f * n0.y, 0.f);
      v2 = fmaxf(a1.x + 0.1f * n1.x, 0.f);
      v3 = fmaxf(a1.y + 0.1f * n1.y, 0.f);
    } else {
      float vv[4];
      int hh = h < 2 ? 3 - h : (h >= 54 ? 107 - h : h);
#pragma unroll
      for (int j = 0; j < 4; j++) {
        int w = col0 + j - 2;
        float v = 0.f;
        if ((unsigned)w < 56u) {
          int ww = w < 2 ? 3 - w : (w >= 54 ? 107 - w : w);
          v = fmaxf(Abase[hh * 56 + ww] + 0.1f * nz[h * 56 + w], 0.f);
        }
        vv[j] = v;
      }
      v0 = vv[0]; v1 = vv[1]; v2 = vv[2]; v3 = vv[3];
    }
    local += v0 + v1 + v2 + v3;
    uint2 w;
    w.x = (unsigned)f2bf(v0) | ((unsigned)f2bf(v1) << 16);
    w.y = (unsigned)f2bf(v2) | ((unsigned)f2bf(v3) << 16);
    *reinterpret_cast<uint2*>(outb + r * 64 + col0) = w;
  }
  int lane = threadIdx.x & 63, wid = threadIdx.x >> 6;
  float v = local;
  for (int off = 32; off; off >>= 1) v += __shfl_down(v, off, 64);
  __shared__ float red[4];
  if (lane == 0) red[wid] = v;
  __syncthreads();
  if (threadIdx.x == 0) s[bc] = red[0] + red[1] + red[2] + red[3];
}

// k2: winners + per-channel batch bitmask + zero Abf guard rings (256 each end)
__global__ __launch_bounds__(512) void k2_winners(const float* __restrict__ s,
                                                  int* __restrict__ fm_idx,
                                                  int* __restrict__ cmask,
                                                  unsigned short* __restrict__ Abf) {
  int t = threadIdx.x;
  {
    int b = t >> 5, f = t & 31;
    float best = s[b * 128 + f];
    int bn = 0;
    for (int n = 1; n < 4; n++) {
      float v = s[b * 128 + n * 32 + f];
      if (v > best) { best = v; bn = n; }
    }
    fm_idx[t] = bn * 32 + f;
  }
  if (t < 256) Abf[t] = 0;
  if (t >= 256) Abf[256 + 7864320 + (t - 256)] = 0;
  __syncthreads();
  if (t < 128) {
    int m = 0;
    for (int b = 0; b < 16; b++)
      if (fm_idx[b * 32 + (t & 31)] == t) m |= (1 << b);
    cmask[t] = m;
  }
}

// k2t: T[b][p][g] = pad_activations(winner g of b) in pixel-major layout
__global__ __launch_bounds__(256) void k2t_transpose(const unsigned short* __restrict__ Abf,
                                                     const int* __restrict__ fm_idx,
                                                     unsigned short* __restrict__ T) {
  __shared__ int win[32];
  int b = blockIdx.x / 15, chunk = blockIdx.x % 15;  // 240 blocks
  if (threadIdx.x < 32) win[threadIdx.x] = fm_idx[b * 32 + threadIdx.x];
  __syncthreads();
  int p = chunk * 256 + threadIdx.x;
  int r = p >> 6, s2 = p & 63;
  int mr = map60(r) + 2;
  int ms = (s2 < 60) ? map60(s2) + 2 : -1;
  unsigned int out[16];
#pragma unroll
  for (int gp = 0; gp < 16; gp++) {
    unsigned short v0 = 0, v1 = 0;
    if (ms >= 0) {
      v0 = Abf[256 + ((size_t)(b * 128) + win[2 * gp]) * 3840 + mr * 64 + ms];
      v1 = Abf[256 + ((size_t)(b * 128) + win[2 * gp + 1]) * 3840 + mr * 64 + ms];
    }
    out[gp] = (unsigned)v0 | ((unsigned)v1 << 16);
  }
  uint4* dst = reinterpret_cast<uint4*>(T + (size_t)b * 122880 + (size_t)p * 32);
#pragma unroll
  for (int q = 0; q < 4; q++) {
    uint4 u;
    u.x = out[4 * q]; u.y = out[4 * q + 1]; u.z = out[4 * q + 2]; u.w = out[4 * q + 3];
    dst[q] = u;
  }
}

// k3: MFMA correlation with register sliding window. Block = (b, kh, mt, nt),
//     bx&15=b (XCD swizzle); 4 waves split K (480 each, 15 ksteps of 32).
//     Steady state: 3 window loads + 1 A load per kstep, 25 MFMAs.
__global__ __launch_bounds__(256, 2) void k3_mfma(const unsigned short* __restrict__ Abf,
                                                  const int* __restrict__ fm_idx,
                                                  float* __restrict__ Kc_b) {
  int bx = blockIdx.x;  // 512: b = bx&15; rr = bx>>4: kh = rr&1, mt = (rr>>1)&1, nt = rr>>2
  int b = bx & 15;
  int rblk = bx >> 4;
  int kh = rblk & 1, mt = (rblk >> 1) & 1, nt = rblk >> 2;
  int wave = threadIdx.x >> 6, lane = threadIdx.x & 63;
  int al = lane & 15, quad = lane >> 4;
  int g0 = mt * 16, a0 = nt * 16;
  int k0 = kh * 1920 + wave * 480;
  floatx4 acc[5][5];
#pragma unroll
  for (int i = 0; i < 5; i++)
#pragma unroll
    for (int j = 0; j < 5; j++) acc[i][j] = (floatx4){0.f, 0.f, 0.f, 0.f};
  int c = fm_idx[b * 32 + g0 + al];
  const unsigned short* pA0 = Abf + 256 + (size_t)(b * 128 + c) * 3840 + k0 + quad * 8;
  const unsigned short* pB0 = Abf + 256 + (size_t)(b * 128 + a0 + al) * 3840 + k0 + quad * 8;

  auto loadwin = [&](unsigned* W, const unsigned short* ptr) {
    W[0] = *reinterpret_cast<const unsigned*>(ptr - 2);   // elems -2..-1
    uint4 m = *reinterpret_cast<const uint4*>(ptr);       // elems  0..7
    W[1] = m.x; W[2] = m.y; W[3] = m.z; W[4] = m.w;
    W[5] = *reinterpret_cast<const unsigned*>(ptr + 8);   // elems  8..9
  };
  auto dostep = [&](unsigned (&W)[5][6], short8 afr) {
#pragma unroll
    for (int dj = 0; dj < 5; dj++) {
      unsigned d0 = W[dj][0], d1 = W[dj][1], d2 = W[dj][2], d3 = W[dj][3],
               d4 = W[dj][4], d5 = W[dj][5];
      unsigned ab0 = __builtin_amdgcn_alignbit(d1, d0, 16);
      unsigned ab1 = __builtin_amdgcn_alignbit(d2, d1, 16);
      unsigned ab2 = __builtin_amdgcn_alignbit(d3, d2, 16);
      unsigned ab3 = __builtin_amdgcn_alignbit(d4, d3, 16);
      unsigned ab4 = __builtin_amdgcn_alignbit(d5, d4, 16);
      acc[0][dj] = __builtin_amdgcn_mfma_f32_16x16x32_bf16(
          afr, u4_to_s8((uint4){d0, d1, d2, d3}), acc[0][dj], 0, 0, 0);
      acc[1][dj] = __builtin_amdgcn_mfma_f32_16x16x32_bf16(
          afr, u4_to_s8((uint4){ab0, ab1, ab2, ab3}), acc[1][dj], 0, 0, 0);
      acc[2][dj] = __builtin_amdgcn_mfma_f32_16x16x32_bf16(
          afr, u4_to_s8((uint4){d1, d2, d3, d4}), acc[2][dj], 0, 0, 0);
      acc[3][dj] = __builtin_amdgcn_mfma_f32_16x16x32_bf16(
          afr, u4_to_s8((uint4){ab1, ab2, ab3, ab4}), acc[3][dj], 0, 0, 0);
      acc[4][dj] = __builtin_amdgcn_mfma_f32_16x16x32_bf16(
          afr, u4_to_s8((uint4){d2, d3, d4, d5}), acc[4][dj], 0, 0, 0);
    }
  };

  unsigned We[5][6], Wo[5][6];
#pragma unroll
  for (int j = 0; j < 5; j++) {
    loadwin(We[j], pB0 + 64 * (j - 2));
    loadwin(Wo[j], pB0 + 64 * (j - 2) + 32);
  }
  short8 afr = *reinterpret_cast<const short8*>(pA0);
#pragma unroll
  for (int ks = 0; ks < 15; ks++) {
    short8 afr_n = afr;
    if (ks < 14) afr_n = *reinterpret_cast<const short8*>(pA0 + 32 * (ks + 1));
    if (ks & 1) dostep(Wo, afr); else dostep(We, afr);
    if (ks & 1) {
      int t = ks >> 1;
#pragma unroll
      for (int j = 0; j < 4; j++)
#pragma unroll
        for (int d = 0; d < 6; d++) {
          We[j][d] = We[j + 1][d];
          Wo[j][d] = Wo[j + 1][d];
        }
      loadwin(We[4], pB0 + 64 * (t + 3));
      loadwin(Wo[4], pB0 + 64 * (t + 3) + 32);
    }
    afr = afr_n;
  }

  __shared__ float red[6400];  // [lane][100]
  float* myrow = red + lane * 100;
  if (wave == 0) {
#pragma unroll
    for (int di = 0; di < 5; di++)
#pragma unroll
      for (int dj = 0; dj < 5; dj++)
#pragma unroll
        for (int r = 0; r < 4; r++) myrow[(di * 5 + dj) * 4 + r] = acc[di][dj][r];
  }
  __syncthreads();
#pragma unroll
  for (int w = 1; w < 4; w++) {
    if (wave == w) {
#pragma unroll
      for (int di = 0; di < 5; di++)
#pragma unroll
        for (int dj = 0; dj < 5; dj++)
#pragma unroll
          for (int r = 0; r < 4; r++) myrow[(di * 5 + dj) * 4 + r] += acc[di][dj][r];
    }
    __syncthreads();
  }
  if (wave == 0) {
    int slot = b * 2 + kh;
#pragma unroll
    for (int di = 0; di < 5; di++)
#pragma unroll
      for (int dj = 0; dj < 5; dj++) {
        int t_out = 24 - (dj * 5 + di);
#pragma unroll
        for (int r = 0; r < 4; r++) {
          int g = g0 + quad * 4 + r;
          Kc_b[(((size_t)slot * 32 + g) * 128 + (a0 + al)) * 25 + t_out] =
              myrow[(di * 5 + dj) * 4 + r] * (1.0f / 2048.0f);
        }
      }
  }
}

// k4 (fused with k4b): per (o,i): kc = sum_slots Kc_b[slot][i&31][o][.] masked
//     by cmask[i]; W2 = minmax25(0.9*K[o][i] + 0.1*minmax25(kc)); scatter bf16
//     into W2g[b][t][f=o&31][g=i&31] for b in cmask[o]&cmask[i].
__global__ __launch_bounds__(256) void k4_weights(const float* __restrict__ Kc_b,
                                                  const float* __restrict__ K,
                                                  const int* __restrict__ cmask,
                                                  unsigned short* __restrict__ W2g) {
  int gid = blockIdx.x * 256 + threadIdx.x;  // 16384
  int o = gid >> 7, i = gid & 127;
  int mi = cmask[i], mo = cmask[o];
  float kc[25];
#pragma unroll
  for (int t = 0; t < 25; t++) kc[t] = 0.f;
  for (int slot = 0; slot < 32; slot++) {
    if ((mi >> (slot >> 1)) & 1) {
      const float* p = Kc_b + (((size_t)slot * 32 + (i & 31)) * 128 + o) * 25;
#pragma unroll
      for (int t = 0; t < 25; t++) kc[t] += p[t];
    }
  }
  float mn = 1e30f, mx = -1e30f;
#pragma unroll
  for (int t = 0; t < 25; t++) { mn = fminf(mn, kc[t]); mx = fmaxf(mx, kc[t]); }
  float d1 = mx - mn + EPSF;
  const float* kp = K + ((size_t)o * 128 + i) * 25;  // K1[i][o] = K[o][i]
  float k2[25], mn2 = 1e30f, mx2 = -1e30f;
#pragma unroll
  for (int t = 0; t < 25; t++) {
    k2[t] = 0.9f * kp[t] + 0.1f * ((kc[t] - mn) / d1);
    mn2 = fminf(mn2, k2[t]);
    mx2 = fmaxf(mx2, k2[t]);
  }
  float d2 = mx2 - mn2 + EPSF;
  unsigned short wb[25];
#pragma unroll
  for (int t = 0; t < 25; t++) wb[t] = f2bf((k2[t] - mn2) / d2);
  int mw = mo & mi;
  int f = o & 31, g = i & 31;
  while (mw) {
    int b = __ffs(mw) - 1;
    mw &= mw - 1;
    unsigned short* dst = W2g + ((size_t)(b * 25) * 32 + f) * 32 + g;
#pragma unroll
    for (int t = 0; t < 25; t++) dst[(size_t)t * 1024] = wb[t];
  }
}

// k5: MFMA conv + gather epilogue. Block = 1 wave = (b, mtile, rowgroup of 4).
__global__ __launch_bounds__(64) void k5_mfma(const unsigned short* __restrict__ W2g,
                                              const unsigned short* __restrict__ T,
                                              const unsigned short* __restrict__ Abf,
                                              const int* __restrict__ fm_idx,
                                              float* __restrict__ O) {
  int bx = blockIdx.x;  // 448 = b(16) x mt(2) x rg(14)
  int rg = bx % 14;
  int mtb = bx / 14;
  int mt = mtb & 1, b = mtb >> 1;
  int lane = threadIdx.x, al = lane & 15, quad = lane >> 4;
  int fm = mt * 16 + al;
  short8 afr[25];
#pragma unroll
  for (int t = 0; t < 25; t++)
    afr[t] = *reinterpret_cast<const short8*>(
        W2g + ((size_t)((b * 25 + t) * 32 + fm) << 5) + quad * 8);
  int orow[4];
#pragma unroll
  for (int r = 0; r < 4; r++) orow[r] = fm_idx[b * 32 + mt * 16 + quad * 4 + r];
  const unsigned short* Tb = T + (size_t)b * 122880;
  for (int rr = 0; rr < 4; rr++) {
    int row = 2 + rg * 4 + rr;
    for (int pair = 0; pair < 2; pair++) {
      int px0 = row * 64 + pair * 32 + al;
      floatx4 acca = (floatx4){0.f, 0.f, 0.f, 0.f};
      floatx4 accb = (floatx4){0.f, 0.f, 0.f, 0.f};
#pragma unroll
      for (int t = 0; t < 25; t++) {
        int off = (t / 5 - 2) * 64 + (t % 5) - 2;
        const short8* pb = reinterpret_cast<const short8*>(
            Tb + (ptrdiff_t)(px0 + off) * 32 + quad * 8);
        short8 b0 = pb[0];
        short8 b1 = pb[64];  // +16 px
        acca = __builtin_amdgcn_mfma_f32_16x16x32_bf16(afr[t], b0, acca, 0, 0, 0);
        accb = __builtin_amdgcn_mfma_f32_16x16x32_bf16(afr[t], b1, accb, 0, 0, 0);
      }
      int h = row - 2;
#pragma unroll
      for (int half = 0; half < 2; half++) {
        floatx4 acc = half ? accb : acca;
        int cc = pair * 32 + half * 16 + al;
        if (cc >= 2 && cc < 58) {
          int w = cc - 2;
          int px = row * 64 + cc;
#pragma unroll
          for (int r = 0; r < 4; r++) {
            int f = mt * 16 + quad * 4 + r;
            float base = bf2f(Abf[256 + (size_t)(b * 128 + orow[r]) * 3840 + px]);
            O[(size_t)(b * 32 + f) * 3136 + h * 56 + w] = base + acc[r] * (0.1f / 32.0f);
          }
        }
      }
    }
  }
}

extern "C" void kernel_launch(void* const* d_in, const int* in_sizes, int n_in,
                              void* d_out, int out_size, void* d_ws, size_t ws_size,
                              hipStream_t stream) {
  const float* A = (const float*)d_in[0];
  const float* K = (const float*)d_in[1];
  const float* noise = (const float*)d_in[2];
  float* O = (float*)d_out;

  float* ws = (float*)d_ws;
  // strictly sequential layout (units: float slots)
  unsigned short* Abf = (unsigned short*)ws;              // [0, 3,932,416)  256+7,864,320+256 us
  float* s = ws + 3932416;                                // [3,932,416, 3,934,464)
  int* fm_idx = (int*)(ws + 3934464);                     // [3,934,464, 3,934,976)  512 ints
  int* cmask = (int*)(ws + 3934976);                      // [3,934,976, 3,935,104)  128 ints
  float* Kc_b = ws + 3935104;                             // [3,935,104, 7,211,904)  32x32x128x25
  unsigned short* T = (unsigned short*)(ws + 7211904);    // [7,211,904, 8,194,944)  1,966,080 us
  unsigned short* W2g = (unsigned short*)(ws + 8194944);  // [8,194,944, 8,399,744)  409,600 us
  // end: 8,399,744 floats = 33.6 MB (ws_size = 256 MiB)

  k1_build<<<2048, 256, 0, stream>>>(A, noise, Abf, s);
  k2_winners<<<1, 512, 0, stream>>>(s, fm_idx, cmask, Abf);
  k2t_transpose<<<240, 256, 0, stream>>>(Abf, fm_idx, T);
  k3_mfma<<<512, 256, 0, stream>>>(Abf, fm_idx, Kc_b);
  k4_weights<<<64, 256, 0, stream>>>(Kc_b, K, cmask, W2g);
  k5_mfma<<<448, 64, 0, stream>>>(W2g, T, Abf, fm_idx, O);
}

// Round 12
// 161.111 us; speedup vs baseline: 1.2207x; 1.2207x over previous
//
#include <hip/hip_runtime.h>

// LaterallyConnectedLayer: B=16, NUM_FM=32, N_REPL=4, C=128, H=W=56, K_SZ=5
// Algebra:
//  - softmax map sums to 1 -> first conv never affects winners -> skipped
//  - winner sparsity: K_change and final conv only touch 32 of 128 channels
//  - padding = index remaps; activations in zero-ring-padded [60][64] frames
// R11: R10's reg sliding window SPILLED (WRITE 13->105 MB scratch). Shift
//      moved to the A side: acc[di][dj] = sum_j A[k+j-(di-2)]*B[k+j+64(dj-2)].
//      B frags = 5 plain aligned loads (row offsets only); 5 A-frags from one
//      6-dword window + 5 shared alignbits. 8 loads/kstep, ~80 live VGPRs,
//      1-deep load pipeline. Same boundary invariant as R9 (zero ring kills
//      chunk-shift residuals and cross-channel overreads).

typedef __attribute__((ext_vector_type(8))) short short8;
typedef __attribute__((ext_vector_type(4))) float floatx4;

#define EPSF 1e-10f

__device__ __forceinline__ int map60(int r) {
  return r < 4 ? 5 - r : (r < 56 ? r - 2 : 109 - r);
}
__device__ __forceinline__ unsigned short f2bf(float x) {
  unsigned int u = __float_as_uint(x);
  u += 0x7fff + ((u >> 16) & 1);
  return (unsigned short)(u >> 16);
}
__device__ __forceinline__ float bf2f(unsigned int h) {
  return __uint_as_float((h & 0xffffu) << 16);
}
__device__ __forceinline__ short8 u4_to_s8(uint4 v) {
  union { uint4 u; short8 s; } cv;
  cv.u = v;
  return cv.s;
}

// k1: Abf[256 + bc*3840 + p] = bf16 zero-ring relu(A_sym + 0.1*noise);
//     s[bc] = fp32 interior sum. Quad-vectorized with scalar edge fallback.
__global__ __launch_bounds__(256) void k1_build(const float* __restrict__ A,
                                                const float* __restrict__ noise,
                                                unsigned short* __restrict__ Abf,
                                                float* __restrict__ s) {
  int bc = blockIdx.x;
  int b = bc >> 7, c = bc & 127;
  int fm = c & 31;
  const float* Abase = A + (size_t)(b * 32 + fm) * 3136;
  const float* nz = noise + (size_t)bc * 3136;
  unsigned short* outb = Abf + 256 + (size_t)bc * 3840;
  float local = 0.f;
  for (int q = threadIdx.x; q < 960; q += 256) {
    int r = q >> 4, qc = q & 15, col0 = qc << 2;
    int h = r - 2;
    float v0, v1, v2, v3;
    if (r < 2 || r > 57 || qc == 15) {
      v0 = v1 = v2 = v3 = 0.f;
    } else if (r >= 4 && r <= 55 && qc >= 1 && qc <= 13) {
      int w0 = col0 - 2;
      const float* ap = Abase + h * 56 + w0;
      const float* np = nz + h * 56 + w0;
      float2 a0 = *reinterpret_cast<const float2*>(ap);
      float2 a1 = *reinterpret_cast<const float2*>(ap + 2);
      float2 n0 = *reinterpret_cast<const float2*>(np);
      float2 n1 = *reinterpret_cast<const float2*>(np + 2);
      v0 = fmaxf(a0.x + 0.1f * n0.x, 0.f);
      v1 = fmaxf(a0.y + 0.1f * n0.y, 0.f);
      v2 = fmaxf(a1.x + 0.1f * n1.x, 0.f);
      v3 = fmaxf(a1.y + 0.1f * n1.y, 0.f);
    } else {
      float vv[4];
      int hh = h < 2 ? 3 - h : (h >= 54 ? 107 - h : h);
#pragma unroll
      for (int j = 0; j < 4; j++) {
        int w = col0 + j - 2;
        float v = 0.f;
        if ((unsigned)w < 56u) {
          int ww = w < 2 ? 3 - w : (w >= 54 ? 107 - w : w);
          v = fmaxf(Abase[hh * 56 + ww] + 0.1f * nz[h * 56 + w], 0.f);
        }
        vv[j] = v;
      }
      v0 = vv[0]; v1 = vv[1]; v2 = vv[2]; v3 = vv[3];
    }
    local += v0 + v1 + v2 + v3;
    uint2 w;
    w.x = (unsigned)f2bf(v0) | ((unsigned)f2bf(v1) << 16);
    w.y = (unsigned)f2bf(v2) | ((unsigned)f2bf(v3) << 16);
    *reinterpret_cast<uint2*>(outb + r * 64 + col0) = w;
  }
  int lane = threadIdx.x & 63, wid = threadIdx.x >> 6;
  float v = local;
  for (int off = 32; off; off >>= 1) v += __shfl_down(v, off, 64);
  __shared__ float red[4];
  if (lane == 0) red[wid] = v;
  __syncthreads();
  if (threadIdx.x == 0) s[bc] = red[0] + red[1] + red[2] + red[3];
}

// k2: winners + per-channel batch bitmask + zero Abf guard rings (256 each end)
__global__ __launch_bounds__(512) void k2_winners(const float* __restrict__ s,
                                                  int* __restrict__ fm_idx,
                                                  int* __restrict__ cmask,
                                                  unsigned short* __restrict__ Abf) {
  int t = threadIdx.x;
  {
    int b = t >> 5, f = t & 31;
    float best = s[b * 128 + f];
    int bn = 0;
    for (int n = 1; n < 4; n++) {
      float v = s[b * 128 + n * 32 + f];
      if (v > best) { best = v; bn = n; }
    }
    fm_idx[t] = bn * 32 + f;
  }
  if (t < 256) Abf[t] = 0;
  if (t >= 256) Abf[256 + 7864320 + (t - 256)] = 0;
  __syncthreads();
  if (t < 128) {
    int m = 0;
    for (int b = 0; b < 16; b++)
      if (fm_idx[b * 32 + (t & 31)] == t) m |= (1 << b);
    cmask[t] = m;
  }
}

// k2t: T[b][p][g] = pad_activations(winner g of b) in pixel-major layout
__global__ __launch_bounds__(256) void k2t_transpose(const unsigned short* __restrict__ Abf,
                                                     const int* __restrict__ fm_idx,
                                                     unsigned short* __restrict__ T) {
  __shared__ int win[32];
  int b = blockIdx.x / 15, chunk = blockIdx.x % 15;  // 240 blocks
  if (threadIdx.x < 32) win[threadIdx.x] = fm_idx[b * 32 + threadIdx.x];
  __syncthreads();
  int p = chunk * 256 + threadIdx.x;
  int r = p >> 6, s2 = p & 63;
  int mr = map60(r) + 2;
  int ms = (s2 < 60) ? map60(s2) + 2 : -1;
  unsigned int out[16];
#pragma unroll
  for (int gp = 0; gp < 16; gp++) {
    unsigned short v0 = 0, v1 = 0;
    if (ms >= 0) {
      v0 = Abf[256 + ((size_t)(b * 128) + win[2 * gp]) * 3840 + mr * 64 + ms];
      v1 = Abf[256 + ((size_t)(b * 128) + win[2 * gp + 1]) * 3840 + mr * 64 + ms];
    }
    out[gp] = (unsigned)v0 | ((unsigned)v1 << 16);
  }
  uint4* dst = reinterpret_cast<uint4*>(T + (size_t)b * 122880 + (size_t)p * 32);
#pragma unroll
  for (int q = 0; q < 4; q++) {
    uint4 u;
    u.x = out[4 * q]; u.y = out[4 * q + 1]; u.z = out[4 * q + 2]; u.w = out[4 * q + 3];
    dst[q] = u;
  }
}

// k3: MFMA correlation, A-side shift. Block = (b, kh, mt, nt), bx&15=b (XCD
//     swizzle); 4 waves split K (480 each, 15 ksteps of 32). Per kstep:
//     3 A-window loads + 5 aligned B loads, 5 alignbits, 25 MFMAs; 1-deep
//     load pipeline. acc[di][dj] = sum A_c[k]*B_a[k+(di-2)+64*(dj-2)].
__global__ __launch_bounds__(256, 2) void k3_mfma(const unsigned short* __restrict__ Abf,
                                                  const int* __restrict__ fm_idx,
                                                  float* __restrict__ Kc_b) {
  int bx = blockIdx.x;  // 512: b = bx&15; rblk = bx>>4: kh, mt, nt
  int b = bx & 15;
  int rblk = bx >> 4;
  int kh = rblk & 1, mt = (rblk >> 1) & 1, nt = rblk >> 2;
  int wave = threadIdx.x >> 6, lane = threadIdx.x & 63;
  int al = lane & 15, quad = lane >> 4;
  int g0 = mt * 16, a0 = nt * 16;
  int k0 = kh * 1920 + wave * 480;
  floatx4 acc[5][5];
#pragma unroll
  for (int i = 0; i < 5; i++)
#pragma unroll
    for (int j = 0; j < 5; j++) acc[i][j] = (floatx4){0.f, 0.f, 0.f, 0.f};
  int c = fm_idx[b * 32 + g0 + al];
  const unsigned short* pA = Abf + 256 + (size_t)(b * 128 + c) * 3840 + k0 + quad * 8;
  const unsigned short* pB = Abf + 256 + (size_t)(b * 128 + a0 + al) * 3840 + k0 + quad * 8;

  auto loadA = [](unsigned* W, const unsigned short* ptr) {
    W[0] = *reinterpret_cast<const unsigned*>(ptr - 2);  // elems -2..-1
    uint4 m = *reinterpret_cast<const uint4*>(ptr);      // elems  0..7
    W[1] = m.x; W[2] = m.y; W[3] = m.z; W[4] = m.w;
    W[5] = *reinterpret_cast<const unsigned*>(ptr + 8);  // elems  8..9
  };

  unsigned Wc[6], Wn[6];
  short8 Bc[5], Bn[5];
  loadA(Wc, pA);
#pragma unroll
  for (int dj = 0; dj < 5; dj++)
    Bc[dj] = *reinterpret_cast<const short8*>(pB + 64 * (dj - 2));
#pragma unroll
  for (int ks = 0; ks < 15; ks++) {
    if (ks < 14) {
      loadA(Wn, pA + 32 * (ks + 1));
#pragma unroll
      for (int dj = 0; dj < 5; dj++)
        Bn[dj] = *reinterpret_cast<const short8*>(pB + 64 * (dj - 2) + 32 * (ks + 1));
    }
    unsigned a10 = __builtin_amdgcn_alignbit(Wc[1], Wc[0], 16);
    unsigned a21 = __builtin_amdgcn_alignbit(Wc[2], Wc[1], 16);
    unsigned a32 = __builtin_amdgcn_alignbit(Wc[3], Wc[2], 16);
    unsigned a43 = __builtin_amdgcn_alignbit(Wc[4], Wc[3], 16);
    unsigned a54 = __builtin_amdgcn_alignbit(Wc[5], Wc[4], 16);
    short8 afr[5];
    afr[0] = u4_to_s8((uint4){Wc[2], Wc[3], Wc[4], Wc[5]});  // A[k+2..k+9]
    afr[1] = u4_to_s8((uint4){a21, a32, a43, a54});          // A[k+1..k+8]
    afr[2] = u4_to_s8((uint4){Wc[1], Wc[2], Wc[3], Wc[4]});  // A[k..k+7]
    afr[3] = u4_to_s8((uint4){a10, a21, a32, a43});          // A[k-1..k+6]
    afr[4] = u4_to_s8((uint4){Wc[0], Wc[1], Wc[2], Wc[3]});  // A[k-2..k+5]
#pragma unroll
    for (int di = 0; di < 5; di++)
#pragma unroll
      for (int dj = 0; dj < 5; dj++)
        acc[di][dj] =
            __builtin_amdgcn_mfma_f32_16x16x32_bf16(afr[di], Bc[dj], acc[di][dj], 0, 0, 0);
    if (ks < 14) {
#pragma unroll
      for (int d = 0; d < 6; d++) Wc[d] = Wn[d];
#pragma unroll
      for (int dj = 0; dj < 5; dj++) Bc[dj] = Bn[dj];
    }
  }

  __shared__ float red[6400];  // [lane][100]
  float* myrow = red + lane * 100;
  if (wave == 0) {
#pragma unroll
    for (int di = 0; di < 5; di++)
#pragma unroll
      for (int dj = 0; dj < 5; dj++)
#pragma unroll
        for (int r = 0; r < 4; r++) myrow[(di * 5 + dj) * 4 + r] = acc[di][dj][r];
  }
  __syncthreads();
#pragma unroll
  for (int w = 1; w < 4; w++) {
    if (wave == w) {
#pragma unroll
      for (int di = 0; di < 5; di++)
#pragma unroll
        for (int dj = 0; dj < 5; dj++)
#pragma unroll
          for (int r = 0; r < 4; r++) myrow[(di * 5 + dj) * 4 + r] += acc[di][dj][r];
    }
    __syncthreads();
  }
  if (wave == 0) {
    int slot = b * 2 + kh;
#pragma unroll
    for (int di = 0; di < 5; di++)
#pragma unroll
      for (int dj = 0; dj < 5; dj++) {
        int t_out = 24 - (dj * 5 + di);
#pragma unroll
        for (int r = 0; r < 4; r++) {
          int g = g0 + quad * 4 + r;
          Kc_b[(((size_t)slot * 32 + g) * 128 + (a0 + al)) * 25 + t_out] =
              myrow[(di * 5 + dj) * 4 + r] * (1.0f / 2048.0f);
        }
      }
  }
}

// k4 (fused with k4b): per (o,i): kc = sum_slots Kc_b[slot][i&31][o][.] masked
//     by cmask[i]; W2 = minmax25(0.9*K[o][i] + 0.1*minmax25(kc)); scatter bf16
//     into W2g[b][t][f=o&31][g=i&31] for b in cmask[o]&cmask[i].
__global__ __launch_bounds__(256) void k4_weights(const float* __restrict__ Kc_b,
                                                  const float* __restrict__ K,
                                                  const int* __restrict__ cmask,
                                                  unsigned short* __restrict__ W2g) {
  int gid = blockIdx.x * 256 + threadIdx.x;  // 16384
  int o = gid >> 7, i = gid & 127;
  int mi = cmask[i], mo = cmask[o];
  float kc[25];
#pragma unroll
  for (int t = 0; t < 25; t++) kc[t] = 0.f;
  for (int slot = 0; slot < 32; slot++) {
    if ((mi >> (slot >> 1)) & 1) {
      const float* p = Kc_b + (((size_t)slot * 32 + (i & 31)) * 128 + o) * 25;
#pragma unroll
      for (int t = 0; t < 25; t++) kc[t] += p[t];
    }
  }
  float mn = 1e30f, mx = -1e30f;
#pragma unroll
  for (int t = 0; t < 25; t++) { mn = fminf(mn, kc[t]); mx = fmaxf(mx, kc[t]); }
  float d1 = mx - mn + EPSF;
  const float* kp = K + ((size_t)o * 128 + i) * 25;  // K1[i][o] = K[o][i]
  float k2[25], mn2 = 1e30f, mx2 = -1e30f;
#pragma unroll
  for (int t = 0; t < 25; t++) {
    k2[t] = 0.9f * kp[t] + 0.1f * ((kc[t] - mn) / d1);
    mn2 = fminf(mn2, k2[t]);
    mx2 = fmaxf(mx2, k2[t]);
  }
  float d2 = mx2 - mn2 + EPSF;
  unsigned short wb[25];
#pragma unroll
  for (int t = 0; t < 25; t++) wb[t] = f2bf((k2[t] - mn2) / d2);
  int mw = mo & mi;
  int f = o & 31, g = i & 31;
  while (mw) {
    int b = __ffs(mw) - 1;
    mw &= mw - 1;
    unsigned short* dst = W2g + ((size_t)(b * 25) * 32 + f) * 32 + g;
#pragma unroll
    for (int t = 0; t < 25; t++) dst[(size_t)t * 1024] = wb[t];
  }
}

// k5: MFMA conv + gather epilogue. Block = 1 wave = (b, mtile, rowgroup of 4).
__global__ __launch_bounds__(64) void k5_mfma(const unsigned short* __restrict__ W2g,
                                              const unsigned short* __restrict__ T,
                                              const unsigned short* __restrict__ Abf,
                                              const int* __restrict__ fm_idx,
                                              float* __restrict__ O) {
  int bx = blockIdx.x;  // 448 = b(16) x mt(2) x rg(14)
  int rg = bx % 14;
  int mtb = bx / 14;
  int mt = mtb & 1, b = mtb >> 1;
  int lane = threadIdx.x, al = lane & 15, quad = lane >> 4;
  int fm = mt * 16 + al;
  short8 afr[25];
#pragma unroll
  for (int t = 0; t < 25; t++)
    afr[t] = *reinterpret_cast<const short8*>(
        W2g + ((size_t)((b * 25 + t) * 32 + fm) << 5) + quad * 8);
  int orow[4];
#pragma unroll
  for (int r = 0; r < 4; r++) orow[r] = fm_idx[b * 32 + mt * 16 + quad * 4 + r];
  const unsigned short* Tb = T + (size_t)b * 122880;
  for (int rr = 0; rr < 4; rr++) {
    int row = 2 + rg * 4 + rr;
    for (int pair = 0; pair < 2; pair++) {
      int px0 = row * 64 + pair * 32 + al;
      floatx4 acca = (floatx4){0.f, 0.f, 0.f, 0.f};
      floatx4 accb = (floatx4){0.f, 0.f, 0.f, 0.f};
#pragma unroll
      for (int t = 0; t < 25; t++) {
        int off = (t / 5 - 2) * 64 + (t % 5) - 2;
        const short8* pb = reinterpret_cast<const short8*>(
            Tb + (ptrdiff_t)(px0 + off) * 32 + quad * 8);
        short8 b0 = pb[0];
        short8 b1 = pb[64];  // +16 px
        acca = __builtin_amdgcn_mfma_f32_16x16x32_bf16(afr[t], b0, acca, 0, 0, 0);
        accb = __builtin_amdgcn_mfma_f32_16x16x32_bf16(afr[t], b1, accb, 0, 0, 0);
      }
      int h = row - 2;
#pragma unroll
      for (int half = 0; half < 2; half++) {
        floatx4 acc = half ? accb : acca;
        int cc = pair * 32 + half * 16 + al;
        if (cc >= 2 && cc < 58) {
          int w = cc - 2;
          int px = row * 64 + cc;
#pragma unroll
          for (int r = 0; r < 4; r++) {
            int f = mt * 16 + quad * 4 + r;
            float base = bf2f(Abf[256 + (size_t)(b * 128 + orow[r]) * 3840 + px]);
            O[(size_t)(b * 32 + f) * 3136 + h * 56 + w] = base + acc[r] * (0.1f / 32.0f);
          }
        }
      }
    }
  }
}

extern "C" void kernel_launch(void* const* d_in, const int* in_sizes, int n_in,
                              void* d_out, int out_size, void* d_ws, size_t ws_size,
                              hipStream_t stream) {
  const float* A = (const float*)d_in[0];
  const float* K = (const float*)d_in[1];
  const float* noise = (const float*)d_in[2];
  float* O = (float*)d_out;

  float* ws = (float*)d_ws;
  // strictly sequential layout (units: float slots)
  unsigned short* Abf = (unsigned short*)ws;              // [0, 3,932,416)  256+7,864,320+256 us
  float* s = ws + 3932416;                                // [3,932,416, 3,934,464)
  int* fm_idx = (int*)(ws + 3934464);                     // [3,934,464, 3,934,976)  512 ints
  int* cmask = (int*)(ws + 3934976);                      // [3,934,976, 3,935,104)  128 ints
  float* Kc_b = ws + 3935104;                             // [3,935,104, 7,211,904)  32x32x128x25
  unsigned short* T = (unsigned short*)(ws + 7211904);    // [7,211,904, 8,194,944)  1,966,080 us
  unsigned short* W2g = (unsigned short*)(ws + 8194944);  // [8,194,944, 8,399,744)  409,600 us
  // end: 8,399,744 floats = 33.6 MB (ws_size = 256 MiB)

  k1_build<<<2048, 256, 0, stream>>>(A, noise, Abf, s);
  k2_winners<<<1, 512, 0, stream>>>(s, fm_idx, cmask, Abf);
  k2t_transpose<<<240, 256, 0, stream>>>(Abf, fm_idx, T);
  k3_mfma<<<512, 256, 0, stream>>>(Abf, fm_idx, Kc_b);
  k4_weights<<<64, 256, 0, stream>>>(Kc_b, K, cmask, W2g);
  k5_mfma<<<448, 64, 0, stream>>>(W2g, T, Abf, fm_idx, O);
}